// Round 1
// baseline (183.780 us; speedup 1.0000x reference)
//
#include <hip/hip_runtime.h>

// XGBoost forest inference: B=50000, F=256, T=1000, depth=6, 127 nodes/tree.
// Design: 64 samples/block staged TRANSPOSED in LDS (conflict-free random
// feature gather: bank = sample%32), trees tiled 64-at-a-time in LDS as
// int2{feat,cond}, 8 waves/block, each thread walks 8 trees concurrently
// for LDS latency hiding. Tree tile index is wave-uniform.

#define NFEAT   256
#define NTREES  1000
#define NNODES  127
#define DEPTH   6
#define SPB     64      // samples per block
#define TILE_T  64      // trees per LDS tile
#define NLANES  8       // tree lanes = 512 threads / 64 samples

template <int W>
__device__ __forceinline__ void walk_trees(const int2* __restrict__ tree,
                                           const float* __restrict__ xs,
                                           int lane, int k, float& acc)
{
    int node[W], toff[W];
#pragma unroll
    for (int j = 0; j < W; ++j) {
        node[j] = 0;
        toff[j] = (lane + (k + j) * NLANES) * NNODES;
    }
#pragma unroll
    for (int d = 0; d < DEPTH; ++d) {
#pragma unroll
        for (int j = 0; j < W; ++j) {
            const int2 nd = tree[toff[j] + node[j]];
            const float xv = xs[nd.x * SPB];
            const float cond = __int_as_float(nd.y);
            node[j] = 2 * node[j] + 1 + (((xv - cond) > 0.0f) ? 1 : 0);
        }
    }
#pragma unroll
    for (int j = 0; j < W; ++j)
        acc += __int_as_float(tree[toff[j] + node[j]].y);
}

__global__ __launch_bounds__(512, 1) void xgb_forest_kernel(
    const float* __restrict__ x,
    const int*   __restrict__ split_idx,
    const float* __restrict__ split_cond,
    const float* __restrict__ base_score,
    float* __restrict__ out, int B)
{
    __shared__ float xT[NFEAT * SPB];        // transposed [feat][sample]  64 KB
    __shared__ int2  tree[TILE_T * NNODES];  // {feat, cond_bits}          63.5 KB
    __shared__ float partials[NLANES * SPB]; //                             2 KB

    const int tid   = threadIdx.x;
    const int sbase = blockIdx.x * SPB;

    // ---- stage x tile, transposed ----
    // wave-instruction = 16 rows x 64B per row: coalesced at line granularity,
    // transposed LDS writes land on 16 distinct banks (4-way, negligible).
    {
        const int sq = tid & 15;   // row within 16-group
        const int cg = tid >> 4;   // 0..31: float4-column group
        for (int rg = 0; rg < 4; ++rg) {
            const int  sl = rg * 16 + sq;
            const bool ok = (sbase + sl) < B;
            for (int ci = 0; ci < 2; ++ci) {
                const int c4 = ci * 32 + cg;
                float4 v = make_float4(0.f, 0.f, 0.f, 0.f);
                if (ok)
                    v = *reinterpret_cast<const float4*>(
                        &x[(size_t)(sbase + sl) * NFEAT + c4 * 4]);
                xT[(c4 * 4 + 0) * SPB + sl] = v.x;
                xT[(c4 * 4 + 1) * SPB + sl] = v.y;
                xT[(c4 * 4 + 2) * SPB + sl] = v.z;
                xT[(c4 * 4 + 3) * SPB + sl] = v.w;
            }
        }
    }

    const int s    = tid & 63;   // sample within block (distinct per lane in wave)
    const int lane = tid >> 6;   // tree lane 0..7, wave-uniform
    const float* xs = &xT[s];    // gather: xs[feat*64] -> bank = s%32, conflict-free

    float acc = 0.0f;

    const int ntiles = (NTREES + TILE_T - 1) / TILE_T;  // 16 (last tile = 40 trees)
    for (int t = 0; t < ntiles; ++t) {
        const int tb   = t * TILE_T;
        const int nT   = min(TILE_T, NTREES - tb);
        const int cnt4 = (nT * NNODES) >> 2;            // always exact (nT*127 % 4 == 0)

        __syncthreads();  // previous tile's readers done (also covers x staging at t=0)
        for (int e4 = tid; e4 < cnt4; e4 += 512) {
            const size_t g = (size_t)tb * NNODES + (size_t)e4 * 4;
            const int4   fi = *reinterpret_cast<const int4*>(&split_idx[g]);
            const float4 fc = *reinterpret_cast<const float4*>(&split_cond[g]);
            tree[e4 * 4 + 0] = make_int2(fi.x, __float_as_int(fc.x));
            tree[e4 * 4 + 1] = make_int2(fi.y, __float_as_int(fc.y));
            tree[e4 * 4 + 2] = make_int2(fi.z, __float_as_int(fc.z));
            tree[e4 * 4 + 3] = make_int2(fi.w, __float_as_int(fc.w));
        }
        __syncthreads();

        // lane handles trees {lane + 8k : 0 <= k < kmax}, kmax wave-uniform
        const int kmax = ((nT - 1 - lane) >> 3) + 1;
        int k = 0;
        for (; k + 8 <= kmax; k += 8) walk_trees<8>(tree, xs, lane, k, acc);
        for (; k + 4 <= kmax; k += 4) walk_trees<4>(tree, xs, lane, k, acc);
        for (; k < kmax; ++k)         walk_trees<1>(tree, xs, lane, k, acc);
    }

    partials[lane * SPB + s] = acc;
    __syncthreads();
    if (tid < SPB) {
        float r = base_score[0];
#pragma unroll
        for (int l = 0; l < NLANES; ++l) r += partials[l * SPB + tid];
        if (sbase + tid < B) out[sbase + tid] = r;
    }
}

extern "C" void kernel_launch(void* const* d_in, const int* in_sizes, int n_in,
                              void* d_out, int out_size, void* d_ws, size_t ws_size,
                              hipStream_t stream)
{
    const float* x          = (const float*)d_in[0];
    const int*   split_idx  = (const int*)d_in[1];
    const float* split_cond = (const float*)d_in[2];
    const float* base_score = (const float*)d_in[3];
    float*       out        = (float*)d_out;

    const int B = out_size;                       // 50000
    const int grid = (B + SPB - 1) / SPB;         // 782

    xgb_forest_kernel<<<grid, 512, 0, stream>>>(x, split_idx, split_cond,
                                                base_score, out, B);
}